// Round 1
// baseline (99.463 us; speedup 1.0000x reference)
//
#include <hip/hip_runtime.h>

// 5-layer MLP: [B,64] -> 32 -> 12 -> 8 -> 6 -> 2, ReLU between, fp32 throughout.
// One thread per row. Weights read via uniform (scalar) loads; row in VGPRs.

template <int IN, int OUT, bool RELU>
__device__ __forceinline__ void layer(const float* __restrict__ W,
                                      const float* __restrict__ b,
                                      const float* h_in, float* h_out) {
#pragma unroll
    for (int o = 0; o < OUT; ++o) h_out[o] = b[o];
#pragma unroll
    for (int i = 0; i < IN; ++i) {
        const float v = h_in[i];
#pragma unroll
        for (int o = 0; o < OUT; ++o) {
            h_out[o] = fmaf(v, W[i * OUT + o], h_out[o]);
        }
    }
    if (RELU) {
#pragma unroll
        for (int o = 0; o < OUT; ++o) h_out[o] = fmaxf(h_out[o], 0.0f);
    }
}

__global__ void mlp_kernel(const float* __restrict__ x,
                           const float* __restrict__ W0, const float* __restrict__ b0,
                           const float* __restrict__ W1, const float* __restrict__ b1,
                           const float* __restrict__ W2, const float* __restrict__ b2,
                           const float* __restrict__ W3, const float* __restrict__ b3,
                           const float* __restrict__ W4, const float* __restrict__ b4,
                           float* __restrict__ out, int nrows) {
    const int row = blockIdx.x * blockDim.x + threadIdx.x;
    if (row >= nrows) return;

    // Load the full 64-float row with 16x float4 loads.
    float xr[64];
    const float4* xv = reinterpret_cast<const float4*>(x + (size_t)row * 64);
#pragma unroll
    for (int k = 0; k < 16; ++k) {
        const float4 v = xv[k];
        xr[4 * k + 0] = v.x;
        xr[4 * k + 1] = v.y;
        xr[4 * k + 2] = v.z;
        xr[4 * k + 3] = v.w;
    }

    float h0[32];
    layer<64, 32, true>(W0, b0, xr, h0);
    float h1[12];
    layer<32, 12, true>(W1, b1, h0, h1);
    float h2[8];
    layer<12, 8, true>(W2, b2, h1, h2);
    float h3[6];
    layer<8, 6, true>(W3, b3, h2, h3);
    float h4[2];
    layer<6, 2, false>(W4, b4, h3, h4);

    // Coalesced 8B store per lane.
    float2* outv = reinterpret_cast<float2*>(out);
    outv[row] = make_float2(h4[0], h4[1]);
}

extern "C" void kernel_launch(void* const* d_in, const int* in_sizes, int n_in,
                              void* d_out, int out_size, void* d_ws, size_t ws_size,
                              hipStream_t stream) {
    const float* x  = (const float*)d_in[0];
    const float* W0 = (const float*)d_in[1];
    const float* b0 = (const float*)d_in[2];
    const float* W1 = (const float*)d_in[3];
    const float* b1 = (const float*)d_in[4];
    const float* W2 = (const float*)d_in[5];
    const float* b2 = (const float*)d_in[6];
    const float* W3 = (const float*)d_in[7];
    const float* b3 = (const float*)d_in[8];
    const float* W4 = (const float*)d_in[9];
    const float* b4 = (const float*)d_in[10];
    float* out = (float*)d_out;

    const int nrows = in_sizes[0] / 64;
    const int block = 256;
    const int grid = (nrows + block - 1) / block;
    mlp_kernel<<<grid, block, 0, stream>>>(x, W0, b0, W1, b1, W2, b2, W3, b3,
                                           W4, b4, out, nrows);
}